// Round 6
// baseline (377.527 us; speedup 1.0000x reference)
//
#include <hip/hip_runtime.h>
#include <hip/hip_bf16.h>

#define D_MODEL 1024
#define N_HEAD  16
#define D_K     64
#define MAX_LEN 1000
#define B_      4
#define S_      1000
#define S_PAD   1024
#define M_PAD   (B_ * S_PAD)       // 4096
#define M_REAL  (B_ * S_)          // 4000
#define LN_EPS  1e-5f
#define SCALE   0.125f
#define REL_ROWS (2*MAX_LEN-1)     // 1999

typedef __attribute__((ext_vector_type(8))) short short8;
typedef __attribute__((ext_vector_type(4))) float f32x4;

__device__ __forceinline__ unsigned short f2b(float f) {
    unsigned u = __builtin_bit_cast(unsigned, f);
    u = (u + 0x7FFFu + ((u >> 16) & 1u)) >> 16;
    return (unsigned short)u;
}

__device__ __forceinline__ float b2f(unsigned short u) {
    return __builtin_bit_cast(float, (unsigned)u << 16);
}

__device__ __forceinline__ f32x4 mfma16(short8 a, short8 b, f32x4 c) {
    return __builtin_amdgcn_mfma_f32_16x16x32_bf16(a, b, c, 0, 0, 0);
}

__device__ __forceinline__ void gload_lds16(const void* g, void* l) {
    __builtin_amdgcn_global_load_lds(
        (const __attribute__((address_space(1))) unsigned int*)g,
        (__attribute__((address_space(3))) unsigned int*)l, 16, 0, 0);
}

// ---------------- fp32 -> bf16 convert ----------------
__global__ void cvt_kernel(const float* __restrict__ in, unsigned short* __restrict__ out, int n4) {
    int i = blockIdx.x * blockDim.x + threadIdx.x;
    if (i >= n4) return;
    float4 v = ((const float4*)in)[i];
    ushort4 o;
    o.x = f2b(v.x); o.y = f2b(v.y); o.z = f2b(v.z); o.w = f2b(v.w);
    ((ushort4*)out)[i] = o;
}

// ---------------- LayerNorm -> bf16, padded rows (i>=1000) zeroed ----------------
__global__ void ln_bf16_kernel(const float* __restrict__ x, const float* __restrict__ g,
                               const float* __restrict__ beta, unsigned short* __restrict__ y) {
    int r = blockIdx.x;            // padded row index
    int b = r >> 10, i = r & 1023;
    unsigned short* yr = y + (size_t)r * D_MODEL;
    int tid = threadIdx.x;
    if (i >= S_) {
#pragma unroll
        for (int l = 0; l < 4; ++l) yr[tid + l * 256] = 0;
        return;
    }
    const float* xr = x + ((size_t)b * S_ + i) * D_MODEL;   // UNPADDED input row
    float v[4];
    float s = 0.f, sq = 0.f;
#pragma unroll
    for (int l = 0; l < 4; ++l) {
        v[l] = xr[tid + l * 256];
        s += v[l];
        sq += v[l] * v[l];
    }
#pragma unroll
    for (int o = 32; o > 0; o >>= 1) {
        s += __shfl_down(s, o, 64);
        sq += __shfl_down(sq, o, 64);
    }
    __shared__ float rs[4], rq[4];
    if ((tid & 63) == 0) { rs[tid >> 6] = s; rq[tid >> 6] = sq; }
    __syncthreads();
    if (tid == 0) {
        rs[0] = rs[0] + rs[1] + rs[2] + rs[3];
        rq[0] = rq[0] + rq[1] + rq[2] + rq[3];
    }
    __syncthreads();
    float mu = rs[0] * (1.0f / D_MODEL);
    float var = rq[0] * (1.0f / D_MODEL) - mu * mu;
    float rstd = rsqrtf(var + LN_EPS);
#pragma unroll
    for (int l = 0; l < 4; ++l) {
        int c = tid + l * 256;
        yr[c] = f2b((v[l] - mu) * rstd * g[c] + beta[c]);
    }
}

// ---------------- bf16 MFMA GEMM (unchanged) ----------------
template<int MODE>
__global__ __launch_bounds__(256) void gemm_bf16(
        const unsigned short* __restrict__ X, const unsigned short* __restrict__ W,
        const float* __restrict__ bias, const float* __restrict__ resid,
        unsigned short* __restrict__ Yb, float* __restrict__ Yf) {
    __shared__ __align__(16) unsigned short As[128 * 32];
    __shared__ __align__(16) unsigned short Bs[128 * 32];
    int tid = threadIdx.x;
    int lane = tid & 63, w = tid >> 6;
    int wr = w >> 1, wc = w & 1;
    int fr = lane & 15, fk = (lane >> 4) * 8;
    int row0 = blockIdx.y * 128, col0 = blockIdx.x * 128;

    f32x4 acc[4][4];
#pragma unroll
    for (int fm = 0; fm < 4; ++fm)
#pragma unroll
        for (int fn = 0; fn < 4; ++fn) acc[fm][fn] = (f32x4)0.f;

    int c0 = (w * 2 + 0) * 64 + lane;
    int c1 = (w * 2 + 1) * 64 + lane;
    const unsigned short* xs0 = X + (size_t)(row0 + (c0 >> 2)) * 1024 + (c0 & 3) * 8;
    const unsigned short* xs1 = X + (size_t)(row0 + (c1 >> 2)) * 1024 + (c1 & 3) * 8;
    const unsigned short* ws0 = W + (size_t)(col0 + (c0 >> 2)) * 1024 + (c0 & 3) * 8;
    const unsigned short* ws1 = W + (size_t)(col0 + (c1 >> 2)) * 1024 + (c1 & 3) * 8;
    unsigned short* ad0 = As + (w * 2 + 0) * 512;
    unsigned short* ad1 = As + (w * 2 + 1) * 512;
    unsigned short* bd0 = Bs + (w * 2 + 0) * 512;
    unsigned short* bd1 = Bs + (w * 2 + 1) * 512;

    for (int k0 = 0; k0 < 1024; k0 += 32) {
        gload_lds16(xs0 + k0, ad0);
        gload_lds16(xs1 + k0, ad1);
        gload_lds16(ws0 + k0, bd0);
        gload_lds16(ws1 + k0, bd1);
        __syncthreads();
        short8 a[4], b[4];
#pragma unroll
        for (int fm = 0; fm < 4; ++fm)
            a[fm] = *(const short8*)(As + (wr * 64 + fm * 16 + fr) * 32 + fk);
#pragma unroll
        for (int fn = 0; fn < 4; ++fn)
            b[fn] = *(const short8*)(Bs + (wc * 64 + fn * 16 + fr) * 32 + fk);
#pragma unroll
        for (int fm = 0; fm < 4; ++fm)
#pragma unroll
            for (int fn = 0; fn < 4; ++fn)
                acc[fm][fn] = mfma16(a[fm], b[fn], acc[fm][fn]);
        __syncthreads();
    }

#pragma unroll
    for (int fm = 0; fm < 4; ++fm) {
#pragma unroll
        for (int fn = 0; fn < 4; ++fn) {
            int cg = col0 + wc * 64 + fn * 16 + fr;
            float bv = bias[cg];
#pragma unroll
            for (int r = 0; r < 4; ++r) {
                int rg = row0 + wr * 64 + fm * 16 + (lane >> 4) * 4 + r;
                float val = acc[fm][fn][r] + bv;
                int b_ = rg >> 10, i = rg & 1023;
                if (MODE == 0) {
                    int h = cg >> 6, d = cg & 63;
                    Yb[(((size_t)(b_ * N_HEAD + h)) * S_PAD + i) * D_K + d] = f2b(val);
                } else if (MODE == 1) {
                    int h = cg >> 6, d = cg & 63;
                    Yb[(((size_t)(b_ * N_HEAD + h)) * D_K + d) * S_PAD + i] = f2b(val);
                } else {
                    if (i < S_) {
                        size_t orow = (size_t)b_ * S_ + i;
                        Yf[orow * 1024 + cg] = val + resid[orow * 1024 + cg];
                    }
                }
            }
        }
    }
}

// ---------------- Flash attention, 128-wide j-tiles ----------------
// One wave per 16-row Q slab; 8 iterations of 128 j each.
#define QRW 148   // ushorts per QR scratch row (143 used)
#define PW  136   // ushorts per P scratch row (128 used)
__global__ __launch_bounds__(256) void attn_mfma(
        const unsigned short* __restrict__ qh, const unsigned short* __restrict__ kh,
        const unsigned short* __restrict__ vt, const unsigned short* __restrict__ relb,
        unsigned short* __restrict__ aout) {
    __shared__ __align__(16) unsigned short QRs[4][16 * QRW];
    __shared__ __align__(16) unsigned short Ps[4][16 * PW];

    int tid = threadIdx.x, lane = tid & 63, w = tid >> 6;
    // XCD-chunked swizzle: 1024 blocks, 128 consecutive logical blocks per XCD
    int bid = blockIdx.x;
    int swz = (bid & 7) * 128 + (bid >> 3);
    int slab = swz * 4 + w;
    int bh = slab >> 6;
    int i0 = (slab & 63) * 16;
    int fr = lane & 15, fk8 = (lane >> 4) * 8, rgrp = (lane >> 4) * 4;

    const unsigned short* qp = qh + ((size_t)bh * S_PAD + i0 + fr) * D_K + fk8;
    short8 aq0 = *(const short8*)(qp);
    short8 aq1 = *(const short8*)(qp + 32);

    f32x4 accO[4];
#pragma unroll
    for (int fd = 0; fd < 4; ++fd) accO[fd] = (f32x4)0.f;
    float mrun[4], lrun[4];
#pragma unroll
    for (int r = 0; r < 4; ++r) { mrun[r] = -3e38f; lrun[r] = 0.f; }

    unsigned short* qrs = QRs[w];
    unsigned short* ps = Ps[w];

    for (int it = 0; it < 8; ++it) {
        int j0 = it * 128;

        // ---- QK^T over 128 j: 8 col-fragments x 2 k-steps ----
        f32x4 accS[8];
#pragma unroll
        for (int fj = 0; fj < 8; ++fj) accS[fj] = (f32x4)0.f;
#pragma unroll
        for (int fj = 0; fj < 8; ++fj) {
            const unsigned short* kp = kh + ((size_t)bh * S_PAD + j0 + fj * 16 + fr) * D_K + fk8;
            accS[fj] = mfma16(aq0, *(const short8*)(kp), accS[fj]);
            accS[fj] = mfma16(aq1, *(const short8*)(kp + 32), accS[fj]);
        }

        // ---- Q @ relband^T: 9 fragments cover cols 0..143 (143 used) ----
        int ub = i0 - j0 + (999 - 127);
#pragma unroll
        for (int fu = 0; fu < 9; ++fu) {
            int u = ub + fu * 16 + fr;
            u = u < 0 ? 0 : (u > REL_ROWS - 1 ? REL_ROWS - 1 : u);
            const unsigned short* rp = relb + (size_t)u * D_K + fk8;
            f32x4 qr = (f32x4)0.f;
            qr = mfma16(aq0, *(const short8*)(rp), qr);
            qr = mfma16(aq1, *(const short8*)(rp + 32), qr);
#pragma unroll
            for (int r = 0; r < 4; ++r)
                qrs[(rgrp + r) * QRW + fu * 16 + fr] = f2b(qr[r]);
        }

        // ---- assemble scores + row max ----
        bool mask_needed = (j0 + 127 >= S_);
        float sc[8][4];
        float pm[4];
#pragma unroll
        for (int r = 0; r < 4; ++r) pm[r] = -3e38f;
#pragma unroll
        for (int fj = 0; fj < 8; ++fj) {
            int j_loc = fj * 16 + fr;
#pragma unroll
            for (int r = 0; r < 4; ++r) {
                int col = rgrp + r - j_loc + 127;   // in [0,142]
                float vv = (accS[fj][r] + b2f(qrs[(rgrp + r) * QRW + col])) * SCALE;
                if (mask_needed && (j0 + j_loc) >= S_) vv = -3e38f;
                sc[fj][r] = vv;
                pm[r] = fmaxf(pm[r], vv);
            }
        }
#pragma unroll
        for (int mask = 1; mask <= 8; mask <<= 1)
#pragma unroll
            for (int r = 0; r < 4; ++r)
                pm[r] = fmaxf(pm[r], __shfl_xor(pm[r], mask, 64));

        // ---- online softmax ----
        float scl[4], rsum[4];
#pragma unroll
        for (int r = 0; r < 4; ++r) {
            float mn = fmaxf(mrun[r], pm[r]);
            scl[r] = __expf(mrun[r] - mn);
            mrun[r] = mn;
            rsum[r] = 0.f;
        }
        // exp + bf16 convert (round-to-nearest f2b, NO cvt_pk asm) + P store
#pragma unroll
        for (int fj = 0; fj < 8; ++fj) {
#pragma unroll
            for (int r = 0; r < 4; ++r) {
                float p = __expf(sc[fj][r] - mrun[r]);
                rsum[r] += p;
                ps[(rgrp + r) * PW + fj * 16 + fr] = f2b(p);
            }
        }
#pragma unroll
        for (int mask = 1; mask <= 8; mask <<= 1)
#pragma unroll
            for (int r = 0; r < 4; ++r)
                rsum[r] += __shfl_xor(rsum[r], mask, 64);
#pragma unroll
        for (int r = 0; r < 4; ++r) lrun[r] = lrun[r] * scl[r] + rsum[r];
#pragma unroll
        for (int fd = 0; fd < 4; ++fd)
#pragma unroll
            for (int r = 0; r < 4; ++r) accO[fd][r] *= scl[r];

        // ---- PV over 128 j: A = P fragments (hoisted), B = V^T ----
        short8 ap[4];
#pragma unroll
        for (int ks = 0; ks < 4; ++ks)
            ap[ks] = *(const short8*)(ps + fr * PW + ks * 32 + fk8);
#pragma unroll
        for (int fd = 0; fd < 4; ++fd) {
            const unsigned short* vp = vt + ((size_t)bh * D_K + fd * 16 + fr) * S_PAD + j0 + fk8;
#pragma unroll
            for (int ks = 0; ks < 4; ++ks)
                accO[fd] = mfma16(ap[ks], *(const short8*)(vp + ks * 32), accO[fd]);
        }
    }

    // ---- normalize + store ----
    int b_ = bh >> 4, h = bh & 15;
#pragma unroll
    for (int r = 0; r < 4; ++r) {
        float inv = 1.0f / lrun[r];
        int m = b_ * S_PAD + i0 + rgrp + r;
#pragma unroll
        for (int fd = 0; fd < 4; ++fd) {
            int c = h * D_K + fd * 16 + fr;
            aout[(size_t)m * D_MODEL + c] = f2b(accO[fd][r] * inv);
        }
    }
}

extern "C" void kernel_launch(void* const* d_in, const int* in_sizes, int n_in,
                              void* d_out, int out_size, void* d_ws, size_t ws_size,
                              hipStream_t stream) {
    const float* q    = (const float*)d_in[0];
    const float* k    = (const float*)d_in[1];
    const float* v    = (const float*)d_in[2];
    const float* ln_g = (const float*)d_in[3];
    const float* ln_b = (const float*)d_in[4];
    const float* wq   = (const float*)d_in[5];
    const float* bq   = (const float*)d_in[6];
    const float* wk   = (const float*)d_in[7];
    const float* bk   = (const float*)d_in[8];
    const float* wv   = (const float*)d_in[9];
    const float* bv   = (const float*)d_in[10];
    const float* wo   = (const float*)d_in[11];
    const float* bo   = (const float*)d_in[12];
    const float* rel  = (const float*)d_in[13];
    float* out = (float*)d_out;

    const size_t TSZ = (size_t)M_PAD * D_MODEL;     // 4,194,304 ushorts
    unsigned short* ws   = (unsigned short*)d_ws;
    unsigned short* qn   = ws;
    unsigned short* kn   = qn + TSZ;
    unsigned short* vn   = kn + TSZ;
    unsigned short* qh   = vn + TSZ;
    unsigned short* kh   = qh + TSZ;
    unsigned short* vt   = kh + TSZ;
    unsigned short* aout = vt + TSZ;
    unsigned short* wqb  = aout + TSZ;
    unsigned short* wkb  = wqb + 1024 * 1024;
    unsigned short* wvb  = wkb + 1024 * 1024;
    unsigned short* wob  = wvb + 1024 * 1024;
    unsigned short* relb = wob + 1024 * 1024;

    cvt_kernel<<<1024, 256, 0, stream>>>(wq, wqb, 262144);
    cvt_kernel<<<1024, 256, 0, stream>>>(wk, wkb, 262144);
    cvt_kernel<<<1024, 256, 0, stream>>>(wv, wvb, 262144);
    cvt_kernel<<<1024, 256, 0, stream>>>(wo, wob, 262144);
    cvt_kernel<<<125, 256, 0, stream>>>(rel, relb, REL_ROWS * D_K / 4);

    ln_bf16_kernel<<<M_PAD, 256, 0, stream>>>(q, ln_g, ln_b, qn);
    ln_bf16_kernel<<<M_PAD, 256, 0, stream>>>(k, ln_g, ln_b, kn);
    ln_bf16_kernel<<<M_PAD, 256, 0, stream>>>(v, ln_g, ln_b, vn);

    dim3 g8(8, 32);
    gemm_bf16<0><<<g8, 256, 0, stream>>>(qn, wqb, bq, nullptr, qh, nullptr);
    gemm_bf16<0><<<g8, 256, 0, stream>>>(kn, wkb, bk, nullptr, kh, nullptr);
    gemm_bf16<1><<<g8, 256, 0, stream>>>(vn, wvb, bv, nullptr, vt, nullptr);

    attn_mfma<<<1024, 256, 0, stream>>>(qh, kh, vt, relb, aout);

    gemm_bf16<2><<<g8, 256, 0, stream>>>(aout, wob, bo, q, nullptr, out);
}

// Round 7
// 231.834 us; speedup vs baseline: 1.6284x; 1.6284x over previous
//
#include <hip/hip_runtime.h>
#include <hip/hip_bf16.h>

#define D_MODEL 1024
#define N_HEAD  16
#define D_K     64
#define MAX_LEN 1000
#define B_      4
#define S_      1000
#define S_PAD   1024
#define M_PAD   (B_ * S_PAD)       // 4096
#define M_REAL  (B_ * S_)          // 4000
#define LN_EPS  1e-5f
#define SCALE   0.125f
#define REL_ROWS (2*MAX_LEN-1)     // 1999

typedef __attribute__((ext_vector_type(8))) short short8;
typedef __attribute__((ext_vector_type(4))) float f32x4;

__device__ __forceinline__ unsigned short f2b(float f) {
    unsigned u = __builtin_bit_cast(unsigned, f);
    u = (u + 0x7FFFu + ((u >> 16) & 1u)) >> 16;
    return (unsigned short)u;
}

__device__ __forceinline__ float b2f(unsigned short u) {
    return __builtin_bit_cast(float, (unsigned)u << 16);
}

__device__ __forceinline__ f32x4 mfma16(short8 a, short8 b, f32x4 c) {
    return __builtin_amdgcn_mfma_f32_16x16x32_bf16(a, b, c, 0, 0, 0);
}

__device__ __forceinline__ void gload_lds16(const void* g, void* l) {
    __builtin_amdgcn_global_load_lds(
        (const __attribute__((address_space(1))) unsigned int*)g,
        (__attribute__((address_space(3))) unsigned int*)l, 16, 0, 0);
}

// ---------------- fp32 -> bf16 convert ----------------
__global__ void cvt_kernel(const float* __restrict__ in, unsigned short* __restrict__ out, int n4) {
    int i = blockIdx.x * blockDim.x + threadIdx.x;
    if (i >= n4) return;
    float4 v = ((const float4*)in)[i];
    ushort4 o;
    o.x = f2b(v.x); o.y = f2b(v.y); o.z = f2b(v.z); o.w = f2b(v.w);
    ((ushort4*)out)[i] = o;
}

// ---------------- LayerNorm -> bf16, padded rows (i>=1000) zeroed ----------------
__global__ void ln_bf16_kernel(const float* __restrict__ x, const float* __restrict__ g,
                               const float* __restrict__ beta, unsigned short* __restrict__ y) {
    int r = blockIdx.x;            // padded row index
    int b = r >> 10, i = r & 1023;
    unsigned short* yr = y + (size_t)r * D_MODEL;
    int tid = threadIdx.x;
    if (i >= S_) {
#pragma unroll
        for (int l = 0; l < 4; ++l) yr[tid + l * 256] = 0;
        return;
    }
    const float* xr = x + ((size_t)b * S_ + i) * D_MODEL;   // UNPADDED input row
    float v[4];
    float s = 0.f, sq = 0.f;
#pragma unroll
    for (int l = 0; l < 4; ++l) {
        v[l] = xr[tid + l * 256];
        s += v[l];
        sq += v[l] * v[l];
    }
#pragma unroll
    for (int o = 32; o > 0; o >>= 1) {
        s += __shfl_down(s, o, 64);
        sq += __shfl_down(sq, o, 64);
    }
    __shared__ float rs[4], rq[4];
    if ((tid & 63) == 0) { rs[tid >> 6] = s; rq[tid >> 6] = sq; }
    __syncthreads();
    if (tid == 0) {
        rs[0] = rs[0] + rs[1] + rs[2] + rs[3];
        rq[0] = rq[0] + rq[1] + rq[2] + rq[3];
    }
    __syncthreads();
    float mu = rs[0] * (1.0f / D_MODEL);
    float var = rq[0] * (1.0f / D_MODEL) - mu * mu;
    float rstd = rsqrtf(var + LN_EPS);
#pragma unroll
    for (int l = 0; l < 4; ++l) {
        int c = tid + l * 256;
        yr[c] = f2b((v[l] - mu) * rstd * g[c] + beta[c]);
    }
}

// ---------------- bf16 MFMA GEMM (unchanged) ----------------
template<int MODE>
__global__ __launch_bounds__(256) void gemm_bf16(
        const unsigned short* __restrict__ X, const unsigned short* __restrict__ W,
        const float* __restrict__ bias, const float* __restrict__ resid,
        unsigned short* __restrict__ Yb, float* __restrict__ Yf) {
    __shared__ __align__(16) unsigned short As[128 * 32];
    __shared__ __align__(16) unsigned short Bs[128 * 32];
    int tid = threadIdx.x;
    int lane = tid & 63, w = tid >> 6;
    int wr = w >> 1, wc = w & 1;
    int fr = lane & 15, fk = (lane >> 4) * 8;
    int row0 = blockIdx.y * 128, col0 = blockIdx.x * 128;

    f32x4 acc[4][4];
#pragma unroll
    for (int fm = 0; fm < 4; ++fm)
#pragma unroll
        for (int fn = 0; fn < 4; ++fn) acc[fm][fn] = (f32x4)0.f;

    int c0 = (w * 2 + 0) * 64 + lane;
    int c1 = (w * 2 + 1) * 64 + lane;
    const unsigned short* xs0 = X + (size_t)(row0 + (c0 >> 2)) * 1024 + (c0 & 3) * 8;
    const unsigned short* xs1 = X + (size_t)(row0 + (c1 >> 2)) * 1024 + (c1 & 3) * 8;
    const unsigned short* ws0 = W + (size_t)(col0 + (c0 >> 2)) * 1024 + (c0 & 3) * 8;
    const unsigned short* ws1 = W + (size_t)(col0 + (c1 >> 2)) * 1024 + (c1 & 3) * 8;
    unsigned short* ad0 = As + (w * 2 + 0) * 512;
    unsigned short* ad1 = As + (w * 2 + 1) * 512;
    unsigned short* bd0 = Bs + (w * 2 + 0) * 512;
    unsigned short* bd1 = Bs + (w * 2 + 1) * 512;

    for (int k0 = 0; k0 < 1024; k0 += 32) {
        gload_lds16(xs0 + k0, ad0);
        gload_lds16(xs1 + k0, ad1);
        gload_lds16(ws0 + k0, bd0);
        gload_lds16(ws1 + k0, bd1);
        __syncthreads();
        short8 a[4], b[4];
#pragma unroll
        for (int fm = 0; fm < 4; ++fm)
            a[fm] = *(const short8*)(As + (wr * 64 + fm * 16 + fr) * 32 + fk);
#pragma unroll
        for (int fn = 0; fn < 4; ++fn)
            b[fn] = *(const short8*)(Bs + (wc * 64 + fn * 16 + fr) * 32 + fk);
#pragma unroll
        for (int fm = 0; fm < 4; ++fm)
#pragma unroll
            for (int fn = 0; fn < 4; ++fn)
                acc[fm][fn] = mfma16(a[fm], b[fn], acc[fm][fn]);
        __syncthreads();
    }

#pragma unroll
    for (int fm = 0; fm < 4; ++fm) {
#pragma unroll
        for (int fn = 0; fn < 4; ++fn) {
            int cg = col0 + wc * 64 + fn * 16 + fr;
            float bv = bias[cg];
#pragma unroll
            for (int r = 0; r < 4; ++r) {
                int rg = row0 + wr * 64 + fm * 16 + (lane >> 4) * 4 + r;
                float val = acc[fm][fn][r] + bv;
                int b_ = rg >> 10, i = rg & 1023;
                if (MODE == 0) {
                    int h = cg >> 6, d = cg & 63;
                    Yb[(((size_t)(b_ * N_HEAD + h)) * S_PAD + i) * D_K + d] = f2b(val);
                } else if (MODE == 1) {
                    int h = cg >> 6, d = cg & 63;
                    Yb[(((size_t)(b_ * N_HEAD + h)) * D_K + d) * S_PAD + i] = f2b(val);
                } else {
                    if (i < S_) {
                        size_t orow = (size_t)b_ * S_ + i;
                        Yf[orow * 1024 + cg] = val + resid[orow * 1024 + cg];
                    }
                }
            }
        }
    }
}

// ---------------- Flash attention, 128-wide j-tiles, LDS-staged K/V ----------------
// 4 waves/block, all sharing one bh; each wave owns 16 q-rows.
// K tile [128 j][64 d] and V^T tile [64 d][128 j] staged per block per j-tile,
// XOR-swizzled (linear LDS dest + pre-swizzled global src, same XOR on read).
#define QRW 148   // QR scratch stride (143 used)
#define PW  136   // P scratch stride (128 used) -- shares buffer with QR
__global__ __launch_bounds__(256) void attn_mfma(
        const unsigned short* __restrict__ qh, const unsigned short* __restrict__ kh,
        const unsigned short* __restrict__ vt, const unsigned short* __restrict__ relb,
        unsigned short* __restrict__ aout) {
    __shared__ __align__(16) unsigned short Ks[128 * 64];   // 16 KB
    __shared__ __align__(16) unsigned short Vs[64 * 128];   // 16 KB
    __shared__ __align__(16) unsigned short QP[4][16 * QRW];// 18.5 KB (QR & P share)

    int tid = threadIdx.x, lane = tid & 63, w = tid >> 6;
    int bid = blockIdx.x;
    int swz = (bid & 7) * 128 + (bid >> 3);   // XCD-chunked swizzle
    int slab = swz * 4 + w;
    int bh = slab >> 6;
    int i0 = (slab & 63) * 16;
    int fr = lane & 15, fk8 = (lane >> 4) * 8, rgrp = (lane >> 4) * 4;
    int rsw = (fr & 7) << 3;                  // read-side XOR (ushort units)

    const unsigned short* kbase = kh + (size_t)bh * S_PAD * D_K;   // [i][d]
    const unsigned short* vtbase = vt + (size_t)bh * D_K * S_PAD;  // [d][i]

    const unsigned short* qp = qh + ((size_t)bh * S_PAD + i0 + fr) * D_K + fk8;
    short8 aq0 = *(const short8*)(qp);
    short8 aq1 = *(const short8*)(qp + 32);

    f32x4 accO[4];
#pragma unroll
    for (int fd = 0; fd < 4; ++fd) accO[fd] = (f32x4)0.f;
    float mrun[4], lrun[4];
#pragma unroll
    for (int r = 0; r < 4; ++r) { mrun[r] = -3e38f; lrun[r] = 0.f; }

    unsigned short* qrs = QP[w];
    unsigned short* ps  = QP[w];   // disjoint lifetime within an iteration

    // staging lane offsets
    int slK = lane ^ ((lane >> 3) & 7);        // K: 8 rows/chunk, 8 slots/row
    int vrow_in = lane >> 4;                   // V: 4 rows/chunk, 16 slots/row

    auto stage = [&](int it2) {
        int j0s = it2 * 128;
        const unsigned short* kg = kbase + j0s * 64;
#pragma unroll
        for (int cc = 0; cc < 4; ++cc) {
            int c = w * 4 + cc;
            gload_lds16(kg + c * 512 + slK * 8, Ks + c * 512);
        }
#pragma unroll
        for (int cc = 0; cc < 4; ++cc) {
            int c = w * 4 + cc;
            int d = c * 4 + vrow_in;
            int sp = (lane & 15) ^ (d & 7);
            gload_lds16(vtbase + (size_t)d * 1024 + j0s + sp * 8, Vs + c * 512);
        }
    };

    stage(0);

    for (int it = 0; it < 8; ++it) {
        int j0 = it * 128;
        __syncthreads();   // drains vmcnt: staged tile visible to all waves

        // ---- QK^T over 128 j from LDS: 8 col-fragments x 2 k-steps ----
        f32x4 accS[8];
#pragma unroll
        for (int fj = 0; fj < 8; ++fj) accS[fj] = (f32x4)0.f;
#pragma unroll
        for (int fj = 0; fj < 8; ++fj) {
            int kb = (fj * 16 + fr) * 64 + fk8;
            accS[fj] = mfma16(aq0, *(const short8*)(Ks + (kb ^ rsw)), accS[fj]);
            accS[fj] = mfma16(aq1, *(const short8*)(Ks + ((kb + 32) ^ rsw)), accS[fj]);
        }

        // ---- Q @ relband^T (global, L2-hot): 9 fragments cover cols 0..143 ----
        int ub = i0 - j0 + (999 - 127);
#pragma unroll
        for (int fu = 0; fu < 9; ++fu) {
            int u = ub + fu * 16 + fr;
            u = u < 0 ? 0 : (u > REL_ROWS - 1 ? REL_ROWS - 1 : u);
            const unsigned short* rp = relb + (size_t)u * D_K + fk8;
            f32x4 qr = (f32x4)0.f;
            qr = mfma16(aq0, *(const short8*)(rp), qr);
            qr = mfma16(aq1, *(const short8*)(rp + 32), qr);
#pragma unroll
            for (int r = 0; r < 4; ++r)
                qrs[(rgrp + r) * QRW + fu * 16 + fr] = f2b(qr[r]);
        }

        // ---- assemble scores + row max ----
        bool mask_needed = (j0 + 127 >= S_);
        float sc[8][4];
        float pm[4];
#pragma unroll
        for (int r = 0; r < 4; ++r) pm[r] = -3e38f;
#pragma unroll
        for (int fj = 0; fj < 8; ++fj) {
            int j_loc = fj * 16 + fr;
#pragma unroll
            for (int r = 0; r < 4; ++r) {
                int col = rgrp + r - j_loc + 127;   // in [0,142]
                float vv = (accS[fj][r] + b2f(qrs[(rgrp + r) * QRW + col])) * SCALE;
                if (mask_needed && (j0 + j_loc) >= S_) vv = -3e38f;
                sc[fj][r] = vv;
                pm[r] = fmaxf(pm[r], vv);
            }
        }
#pragma unroll
        for (int mask = 1; mask <= 8; mask <<= 1)
#pragma unroll
            for (int r = 0; r < 4; ++r)
                pm[r] = fmaxf(pm[r], __shfl_xor(pm[r], mask, 64));

        // ---- online softmax ----
        float scl[4], rsum[4];
#pragma unroll
        for (int r = 0; r < 4; ++r) {
            float mn = fmaxf(mrun[r], pm[r]);
            scl[r] = __expf(mrun[r] - mn);
            mrun[r] = mn;
            rsum[r] = 0.f;
        }
#pragma unroll
        for (int fj = 0; fj < 8; ++fj) {
#pragma unroll
            for (int r = 0; r < 4; ++r) {
                float p = __expf(sc[fj][r] - mrun[r]);
                rsum[r] += p;
                ps[(rgrp + r) * PW + fj * 16 + fr] = f2b(p);
            }
        }
#pragma unroll
        for (int mask = 1; mask <= 8; mask <<= 1)
#pragma unroll
            for (int r = 0; r < 4; ++r)
                rsum[r] += __shfl_xor(rsum[r], mask, 64);
#pragma unroll
        for (int r = 0; r < 4; ++r) lrun[r] = lrun[r] * scl[r] + rsum[r];
#pragma unroll
        for (int fd = 0; fd < 4; ++fd)
#pragma unroll
            for (int r = 0; r < 4; ++r) accO[fd][r] *= scl[r];

        // ---- PV over 128 j: A = P fragments, B = V^T from LDS ----
        short8 ap[4];
#pragma unroll
        for (int ks = 0; ks < 4; ++ks)
            ap[ks] = *(const short8*)(ps + fr * PW + ks * 32 + fk8);
#pragma unroll
        for (int fd = 0; fd < 4; ++fd) {
            int vb = (fd * 16 + fr) * 128 + fk8;
#pragma unroll
            for (int ks = 0; ks < 4; ++ks)
                accO[fd] = mfma16(ap[ks], *(const short8*)(Vs + ((vb + ks * 32) ^ rsw)), accO[fd]);
        }

        __syncthreads();   // all waves done reading Ks/Vs
        if (it < 7) stage(it + 1);
    }

    // ---- normalize + store ----
    int b_ = bh >> 4, h = bh & 15;
#pragma unroll
    for (int r = 0; r < 4; ++r) {
        float inv = 1.0f / lrun[r];
        int m = b_ * S_PAD + i0 + rgrp + r;
#pragma unroll
        for (int fd = 0; fd < 4; ++fd) {
            int c = h * D_K + fd * 16 + fr;
            aout[(size_t)m * D_MODEL + c] = f2b(accO[fd][r] * inv);
        }
    }
}

extern "C" void kernel_launch(void* const* d_in, const int* in_sizes, int n_in,
                              void* d_out, int out_size, void* d_ws, size_t ws_size,
                              hipStream_t stream) {
    const float* q    = (const float*)d_in[0];
    const float* k    = (const float*)d_in[1];
    const float* v    = (const float*)d_in[2];
    const float* ln_g = (const float*)d_in[3];
    const float* ln_b = (const float*)d_in[4];
    const float* wq   = (const float*)d_in[5];
    const float* bq   = (const float*)d_in[6];
    const float* wk   = (const float*)d_in[7];
    const float* bk   = (const float*)d_in[8];
    const float* wv   = (const float*)d_in[9];
    const float* bv   = (const float*)d_in[10];
    const float* wo   = (const float*)d_in[11];
    const float* bo   = (const float*)d_in[12];
    const float* rel  = (const float*)d_in[13];
    float* out = (float*)d_out;

    const size_t TSZ = (size_t)M_PAD * D_MODEL;     // 4,194,304 ushorts
    unsigned short* ws   = (unsigned short*)d_ws;
    unsigned short* qn   = ws;
    unsigned short* kn   = qn + TSZ;
    unsigned short* vn   = kn + TSZ;
    unsigned short* qh   = vn + TSZ;
    unsigned short* kh   = qh + TSZ;
    unsigned short* vt   = kh + TSZ;
    unsigned short* aout = vt + TSZ;
    unsigned short* wqb  = aout + TSZ;
    unsigned short* wkb  = wqb + 1024 * 1024;
    unsigned short* wvb  = wkb + 1024 * 1024;
    unsigned short* wob  = wvb + 1024 * 1024;
    unsigned short* relb = wob + 1024 * 1024;

    cvt_kernel<<<1024, 256, 0, stream>>>(wq, wqb, 262144);
    cvt_kernel<<<1024, 256, 0, stream>>>(wk, wkb, 262144);
    cvt_kernel<<<1024, 256, 0, stream>>>(wv, wvb, 262144);
    cvt_kernel<<<1024, 256, 0, stream>>>(wo, wob, 262144);
    cvt_kernel<<<125, 256, 0, stream>>>(rel, relb, REL_ROWS * D_K / 4);

    ln_bf16_kernel<<<M_PAD, 256, 0, stream>>>(q, ln_g, ln_b, qn);
    ln_bf16_kernel<<<M_PAD, 256, 0, stream>>>(k, ln_g, ln_b, kn);
    ln_bf16_kernel<<<M_PAD, 256, 0, stream>>>(v, ln_g, ln_b, vn);

    dim3 g8(8, 32);
    gemm_bf16<0><<<g8, 256, 0, stream>>>(qn, wqb, bq, nullptr, qh, nullptr);
    gemm_bf16<0><<<g8, 256, 0, stream>>>(kn, wkb, bk, nullptr, kh, nullptr);
    gemm_bf16<1><<<g8, 256, 0, stream>>>(vn, wvb, bv, nullptr, vt, nullptr);

    attn_mfma<<<1024, 256, 0, stream>>>(qh, kh, vt, relb, aout);

    gemm_bf16<2><<<g8, 256, 0, stream>>>(aout, wob, bo, q, nullptr, out);
}